// Round 1
// baseline (167.256 us; speedup 1.0000x reference)
//
#include <hip/hip_runtime.h>

#define BB 256
#define TT 64
#define DD 2048
#define THRESH 0.99f
#define EPS 0.01f

// Output layout in d_out (fp32):
//   [0, B*D)           final_output [B, D]
//   [B*D, B*D+B)       ponder_cost  [B]
//   [B*D+B, +B*T)      weights      [B, T]

__global__ __launch_bounds__(256) void act_halting_kernel(
    const float* __restrict__ halt_probs,    // [B, T, 1]
    const float* __restrict__ outputs,       // [B, T, D]
    const float* __restrict__ step_weights,  // [B, T]
    float* __restrict__ d_out)
{
    const int b   = blockIdx.x;
    const int tid = threadIdx.x;

    __shared__ float s_w[TT];
    __shared__ int   s_hs;

    if (tid < 64) {  // wave 0: per-batch scalar pipeline, T=64 == wave width
        const int lane = tid;
        const float p  = halt_probs[b * TT + lane];
        const float sw = step_weights[b * TT + lane];

        // inclusive cumsum over 64 lanes
        float c = p;
        #pragma unroll
        for (int off = 1; off < 64; off <<= 1) {
            float y = __shfl_up(c, off, 64);
            if (lane >= off) c += y;
        }

        // first lane where cumsum >= threshold, fallback T-1
        unsigned long long m = __ballot(c >= THRESH);
        const int hs = m ? (__ffsll((unsigned long long)m) - 1) : (TT - 1);

        const float cum_at = __shfl(c, hs, 64);
        const float p_at   = __shfl(p, hs, 64);
        const float remaining = 1.0f - cum_at + p_at;

        float w = (lane < hs) ? p : ((lane == hs) ? remaining : 0.0f);
        w *= sw;

        // wave-sum
        float s = w;
        #pragma unroll
        for (int off = 32; off >= 1; off >>= 1) s += __shfl_xor(s, off, 64);
        s = fmaxf(s, EPS);
        w = w / s;

        s_w[lane] = w;
        if (lane == 0) s_hs = hs;

        if (blockIdx.y == 0) {
            d_out[BB * DD + BB + b * TT + lane] = w;   // weights row
            float pc = w * (float)(lane + 1);
            #pragma unroll
            for (int off = 32; off >= 1; off >>= 1) pc += __shfl_xor(pc, off, 64);
            if (lane == 0) d_out[BB * DD + b] = pc;    // ponder_cost
        }
    }
    __syncthreads();

    // einsum over only the live timesteps (w[t] == 0 for t > hs)
    const int hs = s_hs;
    const float4* out4 = (const float4*)(outputs + (size_t)b * (TT * DD));
    const int d4 = blockIdx.y * blockDim.x + tid;   // float4 column, 0..511

    float4 acc = make_float4(0.f, 0.f, 0.f, 0.f);
    for (int t = 0; t <= hs; ++t) {
        const float w = s_w[t];
        const float4 v = out4[t * (DD / 4) + d4];
        acc.x = fmaf(w, v.x, acc.x);
        acc.y = fmaf(w, v.y, acc.y);
        acc.z = fmaf(w, v.z, acc.z);
        acc.w = fmaf(w, v.w, acc.w);
    }
    float4* fo = (float4*)d_out;
    fo[b * (DD / 4) + d4] = acc;
}

extern "C" void kernel_launch(void* const* d_in, const int* in_sizes, int n_in,
                              void* d_out, int out_size, void* d_ws, size_t ws_size,
                              hipStream_t stream) {
    const float* halt_probs   = (const float*)d_in[0];
    const float* outputs      = (const float*)d_in[1];
    const float* step_weights = (const float*)d_in[2];
    float* out = (float*)d_out;

    dim3 grid(BB, 2);   // 2 chunks of D/2 = 1024 floats = 256 float4 per block
    dim3 block(256);
    act_halting_kernel<<<grid, block, 0, stream>>>(halt_probs, outputs, step_weights, out);
}